// Round 3
// baseline (420.077 us; speedup 1.0000x reference)
//
#include <hip/hip_runtime.h>
#include <hip/hip_bf16.h>
#include <math.h>

// MixerBlock on MI355X — R10: k3/k4 move to 256x256 tile, 8 waves, BK=32,
// double-buffered 64KB LDS, counted vmcnt(4) (R9 schedule), XOR-swizzled LDS
// (pre-swizzled global source + swizzled ds_read; both-sides involution).
// Rationale: R7/R8/R9 all land k3 at ~120-128us with every counter <30% —
// latency-bound 128² tile. 256² gives 4x FLOP/staged-byte, 32 MFMA + 12
// ds_read per wave per barrier pair, and a full-iteration (~500cy) vmem
// in-flight window. k1/k2 keep the R9 128² core (shapes don't fit 256²).
#define B_   64
#define P_   196
#define PPAD 224
#define C_   768
#define TM_  384
#define CM_  3072
#define EPSY 0.1f

typedef unsigned short u16;
typedef __attribute__((ext_vector_type(8))) short bf16x8;
typedef __attribute__((ext_vector_type(4))) float f32x4;

__device__ __forceinline__ float bf2f(u16 v) {
    return __uint_as_float(((unsigned int)v) << 16);
}
__device__ __forceinline__ u16 f2bf(float f) {
    unsigned int u = __float_as_uint(f);
    unsigned int rounding = 0x7FFFu + ((u >> 16) & 1u);
    return (u16)((u + rounding) >> 16);
}

__device__ __forceinline__ void gl_lds16(const u16* g, u16* l) {
    __builtin_amdgcn_global_load_lds(
        (const __attribute__((address_space(1))) unsigned int*)g,
        (__attribute__((address_space(3))) unsigned int*)l,
        16, 0, 0);
}

// ---------------- prep ----------------

__global__ __launch_bounds__(256) void k_prep_xT(const float* __restrict__ x,
                                                 u16* __restrict__ xT,
                                                 float* __restrict__ xn1) {
    __shared__ u16 tile[32][33];
    __shared__ float colsum[32];
    const int b = blockIdx.z, p0 = blockIdx.x * 32, c0 = blockIdx.y * 32;
    const int tx = threadIdx.x & 31, ty = threadIdx.x >> 5;
    if (threadIdx.x < 32) colsum[threadIdx.x] = 0.f;
    const float* xb = x + (size_t)b * P_ * C_;
    float s = 0.f;
    #pragma unroll
    for (int r = 0; r < 4; ++r) {
        int p = p0 + ty + r * 8;
        float v = (p < P_) ? xb[(size_t)p * C_ + c0 + tx] : 0.f;
        u16 h = f2bf(v);
        tile[ty + r * 8][tx] = h;
        float vb = bf2f(h);
        s = fmaf(vb, vb, s);
    }
    __syncthreads();
    u16* dst = xT + ((size_t)b * C_ + c0) * PPAD + p0;
    #pragma unroll
    for (int r = 0; r < 4; ++r) {
        int cl = ty + r * 8;
        dst[(size_t)cl * PPAD + tx] = tile[tx][cl];
    }
    atomicAdd(&colsum[tx], s);
    __syncthreads();
    if (threadIdx.x < 32)
        atomicAdd(&xn1[(size_t)b * C_ + c0 + threadIdx.x], colsum[threadIdx.x]);
}

__device__ __forceinline__ void pad_norm_body(const float* in, u16* outb, float* norm,
                                              int rows, int inlen, int outlen,
                                              int bid, int tid) {
    int wave = (bid * 256 + tid) >> 6;
    int lane = tid & 63;
    if (wave >= rows) return;
    const float* src = in + (size_t)wave * inlen;
    u16* dst = outb + (size_t)wave * outlen;
    float s = 0.f;
    for (int i = lane; i < outlen; i += 64) {
        float v = (i < inlen) ? src[i] : 0.f;
        u16 h = f2bf(v);
        dst[i] = h;
        float vv = bf2f(h);
        s = fmaf(vv, vv, s);
    }
    #pragma unroll
    for (int off = 32; off > 0; off >>= 1) s += __shfl_down(s, off, 64);
    if (lane == 0) norm[wave] = s;
}

__global__ __launch_bounds__(256) void k_prep_weights(
    const float* __restrict__ tw, u16* __restrict__ twb, float* __restrict__ twn,
    const float* __restrict__ cw, u16* __restrict__ cwb, float* __restrict__ cwn,
    const float* __restrict__ w2, u16* __restrict__ w2b,
    const float* __restrict__ w4, u16* __restrict__ w4b) {
    int bid = blockIdx.x, tid = threadIdx.x;
    if (bid < 96) {
        pad_norm_body(tw, twb, twn, TM_, P_, PPAD, bid, tid);
    } else if (bid < 864) {
        pad_norm_body(cw, cwb, cwn, CM_, C_, C_, bid - 96, tid);
    } else if (bid < 1248) {
        int idx = (bid - 864) * 256 + tid;
        int row = idx / TM_;
        w2b[idx] = (row < P_) ? f2bf(w2[(size_t)row * TM_ + (idx % TM_)]) : (u16)0;
    } else {
        int idx = (bid - 1248) * 256 + tid;
        float4 v = ((const float4*)w4)[idx];
        ushort4 o;
        o.x = f2bf(v.x); o.y = f2bf(v.y); o.z = f2bf(v.z); o.w = f2bf(v.w);
        ((ushort4*)w4b)[idx] = o;
    }
}

// ---------------- R9 128x128 core (kept for k1/k2) ----------------
__device__ __forceinline__ void mfma_mainloop(
    const u16* __restrict__ A, const u16* __restrict__ B,
    int lda, int ldb, int kiters,
    f32x4 (&acc)[4][4], u16* As, u16* Bs) {
    const int t = threadIdx.x;
    const int w = t >> 6, l = t & 63;
    const int quad = l >> 4, l15 = l & 15;
    const int row0 = t >> 2, kc = (t & 3) * 8;

    const u16* pa0 = A + (size_t)row0 * lda + kc;
    const u16* pa1 = A + (size_t)(64 + row0) * lda + kc;
    const u16* pb0 = B + (size_t)row0 * ldb + kc;
    const u16* pb1 = B + (size_t)(64 + row0) * ldb + kc;

    u16* ldsA0 = As + w * 512;
    u16* ldsA1 = As + 2048 + w * 512;
    u16* ldsB0 = Bs + w * 512;
    u16* ldsB1 = Bs + 2048 + w * 512;

#define STAGE_(bsel, koff)                          \
    do {                                            \
        const int nb_ = (bsel) * 4096;              \
        gl_lds16(pa0 + (koff), ldsA0 + nb_);        \
        gl_lds16(pa1 + (koff), ldsA1 + nb_);        \
        gl_lds16(pb0 + (koff), ldsB0 + nb_);        \
        gl_lds16(pb1 + (koff), ldsB1 + nb_);        \
    } while (0)

    STAGE_(0, 0);
    if (kiters > 1) {
        STAGE_(1, 32);
        asm volatile("s_waitcnt vmcnt(4)" ::: "memory");
    } else {
        asm volatile("s_waitcnt vmcnt(0)" ::: "memory");
    }
    __builtin_amdgcn_s_barrier();

    int cur = 0;
    int koff = 64;
    for (int it = 0; it < kiters; ++it) {
        const u16* Aw = As + cur * 4096 + (w >> 1) * 2048;
        const u16* Bw = Bs + cur * 4096 + (w & 1) * 2048;
        bf16x8 af[4], bfr[4];
        #pragma unroll
        for (int i = 0; i < 4; ++i)
            af[i] = *(const bf16x8*)(Aw + ((i * 16 + l15) * 32 + quad * 8));
        #pragma unroll
        for (int j = 0; j < 4; ++j)
            bfr[j] = *(const bf16x8*)(Bw + ((j * 16 + l15) * 32 + quad * 8));
        asm volatile("s_waitcnt lgkmcnt(0)" ::: "memory");
        __builtin_amdgcn_sched_barrier(0);
        __builtin_amdgcn_s_barrier();
        const bool more2 = (it + 2 < kiters);
        if (more2) { STAGE_(cur, koff); koff += 32; }
        __builtin_amdgcn_s_setprio(1);
        #pragma unroll
        for (int i = 0; i < 4; ++i)
            #pragma unroll
            for (int j = 0; j < 4; ++j)
                acc[i][j] = __builtin_amdgcn_mfma_f32_16x16x32_bf16(af[i], bfr[j], acc[i][j], 0, 0, 0);
        __builtin_amdgcn_s_setprio(0);
        if (it + 1 < kiters) {
            if (more2) asm volatile("s_waitcnt vmcnt(4)" ::: "memory");
            else       asm volatile("s_waitcnt vmcnt(0)" ::: "memory");
            __builtin_amdgcn_s_barrier();
        }
        cur ^= 1;
    }
#undef STAGE_
}

#define MFMA_CORE(AP, BP, LDA, LDB, KITERS)                              \
    __shared__ u16 As[2 * 128 * 32];                                     \
    __shared__ u16 Bs[2 * 128 * 32];                                     \
    const int t = threadIdx.x;                                           \
    const int wid = t >> 6, lane = t & 63;                               \
    const int quad = lane >> 4, l15 = lane & 15;                         \
    f32x4 acc[4][4];                                                     \
    _Pragma("unroll")                                                    \
    for (int i = 0; i < 4; ++i)                                          \
        _Pragma("unroll")                                                \
        for (int j = 0; j < 4; ++j) acc[i][j] = (f32x4){0.f,0.f,0.f,0.f};\
    mfma_mainloop(AP, BP, LDA, LDB, KITERS, acc, As, Bs);                \
    const int rbase = m0 + (wid >> 1) * 64;                              \
    const int cbase = n0 + (wid & 1) * 64;

// ---------------- R10 256x256 core: BK=32, 8 waves, dbuf, swizzled LDS ----------------
// LDS: A [2dbuf][256][32] at 0, B at 16384 el; 65536 u16 = 64KB (2 blocks/CU).
// Swizzle involution on element index within region: e ^= ((e>>5)&3)<<3
// (row bits 0-1 flip the 16B slot). Staging writes LINEAR dest (gl_lds
// requirement) from inverse-swizzled global source; reads apply the XOR.
__device__ __forceinline__ void mfma256_mainloop(
    const u16* __restrict__ A, const u16* __restrict__ B,
    int lda, int ldb, int kiters,
    f32x4 (&acc)[8][4], u16* smem,
    int wr, int wc, int l15, int quad) {
    const int t = threadIdx.x;
    const int cxor = (quad * 8) ^ ((l15 & 3) * 8);

    // staging: element off = j*4096 + t*8 (linear dest); source coords from
    // s = off ^ (((off>>5)&3)<<3): gr = s>>5 (row 0..255), gc = s&31
    const int off0 = t * 8;
    const int s0 = off0 ^ (((off0 >> 5) & 3) << 3);
    const int gr0 = s0 >> 5, gc0 = s0 & 31;
    const int off1 = 4096 + t * 8;
    const int s1 = off1 ^ (((off1 >> 5) & 3) << 3);
    const int gr1 = s1 >> 5, gc1 = s1 & 31;

    const u16* a0 = A + (size_t)gr0 * lda + gc0;
    const u16* a1 = A + (size_t)gr1 * lda + gc1;
    const u16* b0 = B + (size_t)gr0 * ldb + gc0;
    const u16* b1 = B + (size_t)gr1 * ldb + gc1;

#define STG256_(d, k0)                                   \
    do {                                                 \
        u16* sb_ = smem + (d) * 8192;                    \
        gl_lds16(a0 + (k0), sb_ + off0);                 \
        gl_lds16(a1 + (k0), sb_ + off1);                 \
        gl_lds16(b0 + (k0), sb_ + 16384 + off0);         \
        gl_lds16(b1 + (k0), sb_ + 16384 + off1);         \
    } while (0)

    // prologue: tile0 -> buf0, tile1 -> buf1; wait tile0 only
    STG256_(0, 0);
    if (kiters > 1) {
        STG256_(1, 32);
        asm volatile("s_waitcnt vmcnt(4)" ::: "memory");
    } else {
        asm volatile("s_waitcnt vmcnt(0)" ::: "memory");
    }
    __builtin_amdgcn_s_barrier();

    int cur = 0;
    for (int it = 0; it < kiters; ++it) {
        const u16* Ab = smem + cur * 8192;
        const u16* Bb = smem + 16384 + cur * 8192;
        bf16x8 bfr[4];
        #pragma unroll
        for (int n = 0; n < 4; ++n)
            bfr[n] = *(const bf16x8*)(Bb + (wc * 64 + n * 16 + l15) * 32 + cxor);
        __builtin_amdgcn_s_setprio(1);
        #pragma unroll
        for (int m = 0; m < 8; ++m) {
            bf16x8 af = *(const bf16x8*)(Ab + (wr * 128 + m * 16 + l15) * 32 + cxor);
            #pragma unroll
            for (int n = 0; n < 4; ++n)
                acc[m][n] = __builtin_amdgcn_mfma_f32_16x16x32_bf16(af, bfr[n], acc[m][n], 0, 0, 0);
        }
        __builtin_amdgcn_s_setprio(0);
        asm volatile("s_waitcnt lgkmcnt(0)" ::: "memory");
        __builtin_amdgcn_sched_barrier(0);
        __builtin_amdgcn_s_barrier();           // release buf[cur]
        if (it + 2 < kiters) {
            STG256_(cur, (it + 2) * 32);
            asm volatile("s_waitcnt vmcnt(4)" ::: "memory");
            __builtin_amdgcn_s_barrier();       // publish buf[cur^1]
        } else if (it + 1 < kiters) {
            asm volatile("s_waitcnt vmcnt(0)" ::: "memory");
            __builtin_amdgcn_s_barrier();
        }
        cur ^= 1;
    }
#undef STG256_
}

// k1: h1[(b*C+c)][t] = yat(xT, twb); M=49152 N=384 K=224 (R9 core).
__global__ __launch_bounds__(256) void k1_token_yat(
    const u16* __restrict__ xT, const u16* __restrict__ twb,
    const float* __restrict__ tb, const float* __restrict__ twn,
    const float* __restrict__ xn1, const float* __restrict__ alpha, float sb,
    u16* __restrict__ h1) {
    const int m0 = (blockIdx.x + blockIdx.y * 8) * 128;
    const int n0 = blockIdx.z * 128;
    MFMA_CORE(xT + (size_t)m0 * PPAD, twb + (size_t)n0 * PPAD, PPAD, PPAD, PPAD / 32)
    float scale = powf(sqrtf(sb), alpha[0]);
    #pragma unroll
    for (int i = 0; i < 4; ++i) {
        #pragma unroll
        for (int j = 0; j < 4; ++j) {
            int col = cbase + j * 16 + l15;
            float bn = tb[col], wnn = twn[col];
            #pragma unroll
            for (int reg = 0; reg < 4; ++reg) {
                int row = rbase + i * 16 + quad * 4 + reg;
                float dnb = acc[i][j][reg];
                float dot = dnb + bn;
                float dist = wnn + xn1[row] - 2.f * dnb;
                h1[(size_t)row * TM_ + col] = f2bf(scale * dot * dot / (dist + EPSY));
            }
        }
    }
}

// k3: h3 = yat(x1b, cwb); M=12544 N=3072 K=768. 256² tile: grid (8,7,12),
// mt = x + y*8 (XCD stripe, guard <49), n-tile = z. 512 threads.
__global__ __launch_bounds__(512) void k3_chan_yat(
    const u16* __restrict__ x1b, const u16* __restrict__ cwb,
    const float* __restrict__ cb, const float* __restrict__ cwn,
    const float* __restrict__ xn2, const float* __restrict__ alpha, float sb,
    u16* __restrict__ h3) {
    __shared__ __align__(16) u16 smem[32768];
    const int mt = blockIdx.x + blockIdx.y * 8;
    if (mt >= (B_ * P_) / 256) return;
    const int m0 = mt * 256;
    const int n0 = blockIdx.z * 256;
    const int t = threadIdx.x;
    const int wid = t >> 6, l = t & 63;
    const int wr = wid >> 2, wc = wid & 3;
    const int quad = l >> 4, l15 = l & 15;
    f32x4 acc[8][4];
    #pragma unroll
    for (int m = 0; m < 8; ++m)
        #pragma unroll
        for (int n = 0; n < 4; ++n) acc[m][n] = (f32x4){0.f, 0.f, 0.f, 0.f};
    mfma256_mainloop(x1b + (size_t)m0 * C_, cwb + (size_t)n0 * C_,
                     C_, C_, C_ / 32, acc, smem, wr, wc, l15, quad);
    const int rbase = m0 + wr * 128;
    const int cbase = n0 + wc * 64;
    float scale = powf(sqrtf(sb), alpha[0]);
    #pragma unroll
    for (int m = 0; m < 8; ++m) {
        #pragma unroll
        for (int n = 0; n < 4; ++n) {
            int col = cbase + n * 16 + l15;
            float bn = cb[col], wnn = cwn[col];
            #pragma unroll
            for (int reg = 0; reg < 4; ++reg) {
                int row = rbase + m * 16 + quad * 4 + reg;
                float dnb = acc[m][n][reg];
                float dot = dnb + bn;
                float dist = wnn + xn2[row] - 2.f * dnb;
                h3[(size_t)row * CM_ + col] = f2bf(scale * dot * dot / (dist + EPSY));
            }
        }
    }
}

// k2: x1b = bf16(x + w2 . h1[b]^T + b2); fused xn2 row-norm atomics (R9 core).
__global__ __launch_bounds__(256) void k2_token_out(
    const u16* __restrict__ w2b, const u16* __restrict__ h1,
    const float* __restrict__ b2, const float* __restrict__ x,
    float* __restrict__ xn2, u16* __restrict__ x1b) {
    const int m0 = blockIdx.x * 128, n0 = blockIdx.y * 128;
    const u16* Bz = h1 + (size_t)blockIdx.z * C_ * TM_;
    MFMA_CORE(w2b + (size_t)m0 * TM_, Bz + (size_t)n0 * TM_, TM_, TM_, TM_ / 32)
    const float* rz = x + (size_t)blockIdx.z * P_ * C_;
    u16* oz = x1b + (size_t)blockIdx.z * P_ * C_;
    float* xrow = xn2 + (size_t)blockIdx.z * P_;
    #pragma unroll
    for (int i = 0; i < 4; ++i) {
        #pragma unroll
        for (int reg = 0; reg < 4; ++reg) {
            int row = rbase + i * 16 + quad * 4 + reg;
            if (row < P_) {
                float bm = b2[row];
                float s = 0.f;
                #pragma unroll
                for (int j = 0; j < 4; ++j) {
                    int col = cbase + j * 16 + l15;
                    float v = acc[i][j][reg] + bm + rz[(size_t)row * C_ + col];
                    u16 h = f2bf(v);
                    oz[(size_t)row * C_ + col] = h;
                    float vb = bf2f(h);
                    s = fmaf(vb, vb, s);
                }
                s += __shfl_xor(s, 1, 64);
                s += __shfl_xor(s, 2, 64);
                s += __shfl_xor(s, 4, 64);
                s += __shfl_xor(s, 8, 64);
                if (l15 == 0) atomicAdd(&xrow[row], s);
            }
        }
    }
}

// k4 split-K on 256² core: grid (8,7,3*nsplit): n0 = (z%3)*256, ks = z/3.
__global__ __launch_bounds__(512) void k4_split(
    const u16* __restrict__ h3, const u16* __restrict__ w4b,
    u16* __restrict__ pbuf, int KK) {
    __shared__ __align__(16) u16 smem[32768];
    const int mt = blockIdx.x + blockIdx.y * 8;
    if (mt >= (B_ * P_) / 256) return;
    const int m0 = mt * 256;
    const int nz = blockIdx.z;
    const int n0 = (nz % 3) * 256;
    const int ks = nz / 3;
    const int kbase = ks * KK;
    const int t = threadIdx.x;
    const int wid = t >> 6, l = t & 63;
    const int wr = wid >> 2, wc = wid & 3;
    const int quad = l >> 4, l15 = l & 15;
    f32x4 acc[8][4];
    #pragma unroll
    for (int m = 0; m < 8; ++m)
        #pragma unroll
        for (int n = 0; n < 4; ++n) acc[m][n] = (f32x4){0.f, 0.f, 0.f, 0.f};
    mfma256_mainloop(h3 + (size_t)m0 * CM_ + kbase, w4b + (size_t)n0 * CM_ + kbase,
                     CM_, CM_, KK / 32, acc, smem, wr, wc, l15, quad);
    const int rbase = m0 + wr * 128;
    const int cbase = n0 + wc * 64;
    u16* dst = pbuf + (size_t)ks * ((size_t)B_ * P_ * C_);
    #pragma unroll
    for (int m = 0; m < 8; ++m) {
        #pragma unroll
        for (int n = 0; n < 4; ++n) {
            int col = cbase + n * 16 + l15;
            #pragma unroll
            for (int reg = 0; reg < 4; ++reg) {
                int row = rbase + m * 16 + quad * 4 + reg;
                dst[(size_t)row * C_ + col] = f2bf(acc[m][n][reg]);
            }
        }
    }
}

// reduce: out = sum(bf16 pbuf[0..NS-1]) + bf2f(x1b) + b4
template <int NS>
__global__ __launch_bounds__(256) void k4_reduce(
    float* __restrict__ outp, const u16* __restrict__ pbuf,
    const u16* __restrict__ x1b, const float* __restrict__ b4) {
    int idx = blockIdx.x * 256 + threadIdx.x;      // < B*P*C/4
    int c = (idx * 4) % C_;
    ushort4 r = ((const ushort4*)x1b)[idx];
    float4 o;
    o.x = bf2f(r.x) + b4[c + 0];
    o.y = bf2f(r.y) + b4[c + 1];
    o.z = bf2f(r.z) + b4[c + 2];
    o.w = bf2f(r.w) + b4[c + 3];
    const size_t stride4 = (size_t)B_ * P_ * C_ / 4;
    #pragma unroll
    for (int s = 0; s < NS; ++s) {
        ushort4 p = ((const ushort4*)pbuf)[idx + s * stride4];
        o.x += bf2f(p.x); o.y += bf2f(p.y); o.z += bf2f(p.z); o.w += bf2f(p.w);
    }
    ((float4*)outp)[idx] = o;
}

// fallback k4 (tiny ws): 128x64 tile BK=32
__global__ __launch_bounds__(256) void gemm_k4_fb(
    const u16* __restrict__ A, const u16* __restrict__ Bmat,
    const float* __restrict__ biasN, const u16* __restrict__ resB,
    float* __restrict__ Fout) {
    __shared__ u16 As[128 * 32];
    __shared__ u16 Bs[64 * 32];
    const int t = threadIdx.x;
    const int wid = t >> 6, lane = t & 63;
    const int quad = lane >> 4, l15 = lane & 15;
    const int m0 = blockIdx.x * 128, n0 = blockIdx.y * 64;
    f32x4 acc[4][2];
    #pragma unroll
    for (int i = 0; i < 4; ++i)
        #pragma unroll
        for (int j = 0; j < 2; ++j) acc[i][j] = (f32x4){0.f, 0.f, 0.f, 0.f};
    const u16* Aw = As + (wid >> 1) * (64 * 32);
    const u16* Bw = Bs + (wid & 1) * (32 * 32);
    const int arow = t >> 2, akc = (t & 3) * 8;
    for (int k0 = 0; k0 < CM_; k0 += 32) {
        gl_lds16(A + (size_t)(m0 + arow) * CM_ + k0 + akc,      As + wid * 512);
        gl_lds16(A + (size_t)(m0 + 64 + arow) * CM_ + k0 + akc, As + 2048 + wid * 512);
        gl_lds16(Bmat + (size_t)(n0 + arow) * CM_ + k0 + akc,   Bs + wid * 512);
        __syncthreads();
        bf16x8 af[4], bfr[2];
        #pragma unroll
        for (int i = 0; i < 4; ++i)
            af[i] = *(const bf16x8*)(Aw + ((i * 16 + l15) * 32 + quad * 8));
        #pragma unroll
        for (int j = 0; j < 2; ++j)
            bfr[j] = *(const bf16x8*)(Bw + ((j * 16 + l15) * 32 + quad * 8));
        #pragma unroll
        for (int i = 0; i < 4; ++i)
            #pragma unroll
            for (int j = 0; j < 2; ++j)
                acc[i][j] = __builtin_amdgcn_mfma_f32_16x16x32_bf16(af[i], bfr[j], acc[i][j], 0, 0, 0);
        __syncthreads();
    }
    const int rbase = m0 + (wid >> 1) * 64;
    const int cbase = n0 + (wid & 1) * 32;
    #pragma unroll
    for (int i = 0; i < 4; ++i) {
        #pragma unroll
        for (int j = 0; j < 2; ++j) {
            int col = cbase + j * 16 + l15;
            float bn = biasN[col];
            #pragma unroll
            for (int reg = 0; reg < 4; ++reg) {
                int row = rbase + i * 16 + quad * 4 + reg;
                float v = acc[i][j][reg] + bn + bf2f(resB[(size_t)row * C_ + col]);
                Fout[(size_t)row * C_ + col] = v;
            }
        }
    }
}

extern "C" void kernel_launch(void* const* d_in, const int* in_sizes, int n_in,
                              void* d_out, int out_size, void* d_ws, size_t ws_size,
                              hipStream_t stream) {
    const float* x  = (const float*)d_in[0];
    const float* tw = (const float*)d_in[1];
    const float* tb = (const float*)d_in[2];
    const float* ta = (const float*)d_in[3];
    const float* w2 = (const float*)d_in[4];
    const float* b2 = (const float*)d_in[5];
    const float* cw = (const float*)d_in[6];
    const float* cb = (const float*)d_in[7];
    const float* ca = (const float*)d_in[8];
    const float* w4 = (const float*)d_in[9];
    const float* b4 = (const float*)d_in[10];
    float* out = (float*)d_out;

    // ---- workspace layout (aliased) ----
    char* ws = (char*)d_ws;
    u16* h1 = (u16*)ws;                                    // B*C*TM (37.7 MB)
    u16* xT = (u16*)(ws + 37748736);                       // (B*C) x 224 (22 MB)
    u16* h3 = (u16*)ws;                                    // (B*P) x CM (77 MB)
    size_t off = 77070336;
    u16* x1b = (u16*)(ws + off); off += (size_t)B_ * P_ * C_ * 2;
    u16* twb = (u16*)(ws + off); off += (size_t)TM_ * PPAD * 2;
    u16* w2b = (u16*)(ws + off); off += (size_t)256 * TM_ * 2;
    u16* cwb = (u16*)(ws + off); off += (size_t)CM_ * C_ * 2;
    u16* w4b = (u16*)(ws + off); off += (size_t)C_ * CM_ * 2;
    float* xn1 = (float*)(ws + off); off += (size_t)B_ * C_ * 4;
    float* xn2 = (float*)(ws + off); off += (size_t)B_ * P_ * 4;
    float* twn = (float*)(ws + off); off += (size_t)TM_ * 4;
    float* cwn = (float*)(ws + off); off += (size_t)CM_ * 4;
    u16* pbuf = (u16*)(ws + off);                          // bf16 split-K partials
    const size_t psz = (size_t)B_ * P_ * C_ * 2;           // 19,267,584 per buffer

    int nsplit = 1;
    if (ws_size >= off + 4 * psz)      nsplit = 4;
    else if (ws_size >= off + 2 * psz) nsplit = 2;

    const float SBT = (float)TM_ / logf((float)TM_ + 1.0f);
    const float SBC = (float)CM_ / logf((float)CM_ + 1.0f);

    // ---- prep ----
    hipMemsetAsync(xn1, 0, (size_t)(B_ * C_ + B_ * P_) * 4, stream);
    k_prep_weights<<<3552, 256, 0, stream>>>(tw, twb, twn, cw, cwb, cwn,
                                             w2, w2b, w4, w4b);
    k_prep_xT<<<dim3(PPAD / 32, C_ / 32, B_), 256, 0, stream>>>(x, xT, xn1);

    // ---- k1: M=49152 N=384 K=224 ; XCD-swizzled grid (8,48,3) ----
    k1_token_yat<<<dim3(8, 48, 3), 256, 0, stream>>>(
        xT, twb, tb, twn, xn1, ta, SBT, h1);

    // ---- k2: M=256 N=768 K=384, per-batch ----
    k2_token_out<<<dim3(2, C_ / 128, B_), 256, 0, stream>>>(
        w2b, h1, b2, x, xn2, x1b);

    // ---- k3: M=12544 N=3072 K=768 ; 256² tile, XCD-swizzled grid (8,7,12) ----
    k3_chan_yat<<<dim3(8, 7, 12), 512, 0, stream>>>(
        x1b, cwb, cb, cwn, xn2, ca, SBC, h3);

    // ---- k4: M=12544 N=768 K=3072, split-K bf16 partials, 256² tile ----
    if (nsplit > 1) {
        k4_split<<<dim3(8, 7, 3 * nsplit), 512, 0, stream>>>(
            h3, w4b, pbuf, CM_ / nsplit);
        int n4 = B_ * P_ * C_ / 4;
        if (nsplit == 4)
            k4_reduce<4><<<(n4 + 255) / 256, 256, 0, stream>>>(out, pbuf, x1b, b4);
        else
            k4_reduce<2><<<(n4 + 255) / 256, 256, 0, stream>>>(out, pbuf, x1b, b4);
    } else {
        gemm_k4_fb<<<dim3(B_ * P_ / 128, C_ / 64), 256, 0, stream>>>(
            h3, w4b, b4, x1b, out);
    }
}

// Round 4
// 366.206 us; speedup vs baseline: 1.1471x; 1.1471x over previous
//
#include <hip/hip_runtime.h>
#include <hip/hip_bf16.h>
#include <math.h>

// MixerBlock on MI355X — R11: true m201 8-phase 256x256/BK=64 core for k3/k4.
// R9/R10 coarse schedules regressed k3 (m196 predicted: coarse split without
// per-phase ds_read∥stage∥MFMA interleave hurts). This is the verified
// template: 8 phases/iter (2 K-tiles), per phase {ds_read subtile; stage 1
// half-tile via global_load_lds; barrier; lgkm(0); setprio; 16 MFMA; setprio;
// barrier}, vmcnt(6) only at phases 4/8, full conflict-free LDS swizzle
// col ^= (row&7)<<3 applied as pre-swizzled global source + swizzled read.
// k1/k2 keep the R9 128² core.
#define B_   64
#define P_   196
#define PPAD 224
#define C_   768
#define TM_  384
#define CM_  3072
#define EPSY 0.1f

typedef unsigned short u16;
typedef __attribute__((ext_vector_type(8))) short bf16x8;
typedef __attribute__((ext_vector_type(4))) float f32x4;

__device__ __forceinline__ float bf2f(u16 v) {
    return __uint_as_float(((unsigned int)v) << 16);
}
__device__ __forceinline__ u16 f2bf(float f) {
    unsigned int u = __float_as_uint(f);
    unsigned int rounding = 0x7FFFu + ((u >> 16) & 1u);
    return (u16)((u + rounding) >> 16);
}

__device__ __forceinline__ void gl_lds16(const u16* g, u16* l) {
    __builtin_amdgcn_global_load_lds(
        (const __attribute__((address_space(1))) unsigned int*)g,
        (__attribute__((address_space(3))) unsigned int*)l,
        16, 0, 0);
}

// ---------------- prep ----------------

__global__ __launch_bounds__(256) void k_prep_xT(const float* __restrict__ x,
                                                 u16* __restrict__ xT,
                                                 float* __restrict__ xn1) {
    __shared__ u16 tile[32][33];
    __shared__ float colsum[32];
    const int b = blockIdx.z, p0 = blockIdx.x * 32, c0 = blockIdx.y * 32;
    const int tx = threadIdx.x & 31, ty = threadIdx.x >> 5;
    if (threadIdx.x < 32) colsum[threadIdx.x] = 0.f;
    const float* xb = x + (size_t)b * P_ * C_;
    float s = 0.f;
    #pragma unroll
    for (int r = 0; r < 4; ++r) {
        int p = p0 + ty + r * 8;
        float v = (p < P_) ? xb[(size_t)p * C_ + c0 + tx] : 0.f;
        u16 h = f2bf(v);
        tile[ty + r * 8][tx] = h;
        float vb = bf2f(h);
        s = fmaf(vb, vb, s);
    }
    __syncthreads();
    u16* dst = xT + ((size_t)b * C_ + c0) * PPAD + p0;
    #pragma unroll
    for (int r = 0; r < 4; ++r) {
        int cl = ty + r * 8;
        dst[(size_t)cl * PPAD + tx] = tile[tx][cl];
    }
    atomicAdd(&colsum[tx], s);
    __syncthreads();
    if (threadIdx.x < 32)
        atomicAdd(&xn1[(size_t)b * C_ + c0 + threadIdx.x], colsum[threadIdx.x]);
}

__device__ __forceinline__ void pad_norm_body(const float* in, u16* outb, float* norm,
                                              int rows, int inlen, int outlen,
                                              int bid, int tid) {
    int wave = (bid * 256 + tid) >> 6;
    int lane = tid & 63;
    if (wave >= rows) return;
    const float* src = in + (size_t)wave * inlen;
    u16* dst = outb + (size_t)wave * outlen;
    float s = 0.f;
    for (int i = lane; i < outlen; i += 64) {
        float v = (i < inlen) ? src[i] : 0.f;
        u16 h = f2bf(v);
        dst[i] = h;
        float vv = bf2f(h);
        s = fmaf(vv, vv, s);
    }
    #pragma unroll
    for (int off = 32; off > 0; off >>= 1) s += __shfl_down(s, off, 64);
    if (lane == 0) norm[wave] = s;
}

__global__ __launch_bounds__(256) void k_prep_weights(
    const float* __restrict__ tw, u16* __restrict__ twb, float* __restrict__ twn,
    const float* __restrict__ cw, u16* __restrict__ cwb, float* __restrict__ cwn,
    const float* __restrict__ w2, u16* __restrict__ w2b,
    const float* __restrict__ w4, u16* __restrict__ w4b) {
    int bid = blockIdx.x, tid = threadIdx.x;
    if (bid < 96) {
        pad_norm_body(tw, twb, twn, TM_, P_, PPAD, bid, tid);
    } else if (bid < 864) {
        pad_norm_body(cw, cwb, cwn, CM_, C_, C_, bid - 96, tid);
    } else if (bid < 1248) {
        int idx = (bid - 864) * 256 + tid;
        int row = idx / TM_;
        w2b[idx] = (row < P_) ? f2bf(w2[(size_t)row * TM_ + (idx % TM_)]) : (u16)0;
    } else {
        int idx = (bid - 1248) * 256 + tid;
        float4 v = ((const float4*)w4)[idx];
        ushort4 o;
        o.x = f2bf(v.x); o.y = f2bf(v.y); o.z = f2bf(v.z); o.w = f2bf(v.w);
        ((ushort4*)w4b)[idx] = o;
    }
}

// ---------------- R9 128x128 core (kept for k1/k2) ----------------
__device__ __forceinline__ void mfma_mainloop(
    const u16* __restrict__ A, const u16* __restrict__ B,
    int lda, int ldb, int kiters,
    f32x4 (&acc)[4][4], u16* As, u16* Bs) {
    const int t = threadIdx.x;
    const int w = t >> 6, l = t & 63;
    const int quad = l >> 4, l15 = l & 15;
    const int row0 = t >> 2, kc = (t & 3) * 8;

    const u16* pa0 = A + (size_t)row0 * lda + kc;
    const u16* pa1 = A + (size_t)(64 + row0) * lda + kc;
    const u16* pb0 = B + (size_t)row0 * ldb + kc;
    const u16* pb1 = B + (size_t)(64 + row0) * ldb + kc;

    u16* ldsA0 = As + w * 512;
    u16* ldsA1 = As + 2048 + w * 512;
    u16* ldsB0 = Bs + w * 512;
    u16* ldsB1 = Bs + 2048 + w * 512;

#define STAGE_(bsel, koff)                          \
    do {                                            \
        const int nb_ = (bsel) * 4096;              \
        gl_lds16(pa0 + (koff), ldsA0 + nb_);        \
        gl_lds16(pa1 + (koff), ldsA1 + nb_);        \
        gl_lds16(pb0 + (koff), ldsB0 + nb_);        \
        gl_lds16(pb1 + (koff), ldsB1 + nb_);        \
    } while (0)

    STAGE_(0, 0);
    if (kiters > 1) {
        STAGE_(1, 32);
        asm volatile("s_waitcnt vmcnt(4)" ::: "memory");
    } else {
        asm volatile("s_waitcnt vmcnt(0)" ::: "memory");
    }
    __builtin_amdgcn_s_barrier();

    int cur = 0;
    int koff = 64;
    for (int it = 0; it < kiters; ++it) {
        const u16* Aw = As + cur * 4096 + (w >> 1) * 2048;
        const u16* Bw = Bs + cur * 4096 + (w & 1) * 2048;
        bf16x8 af[4], bfr[4];
        #pragma unroll
        for (int i = 0; i < 4; ++i)
            af[i] = *(const bf16x8*)(Aw + ((i * 16 + l15) * 32 + quad * 8));
        #pragma unroll
        for (int j = 0; j < 4; ++j)
            bfr[j] = *(const bf16x8*)(Bw + ((j * 16 + l15) * 32 + quad * 8));
        asm volatile("s_waitcnt lgkmcnt(0)" ::: "memory");
        __builtin_amdgcn_sched_barrier(0);
        __builtin_amdgcn_s_barrier();
        const bool more2 = (it + 2 < kiters);
        if (more2) { STAGE_(cur, koff); koff += 32; }
        __builtin_amdgcn_s_setprio(1);
        #pragma unroll
        for (int i = 0; i < 4; ++i)
            #pragma unroll
            for (int j = 0; j < 4; ++j)
                acc[i][j] = __builtin_amdgcn_mfma_f32_16x16x32_bf16(af[i], bfr[j], acc[i][j], 0, 0, 0);
        __builtin_amdgcn_s_setprio(0);
        if (it + 1 < kiters) {
            if (more2) asm volatile("s_waitcnt vmcnt(4)" ::: "memory");
            else       asm volatile("s_waitcnt vmcnt(0)" ::: "memory");
            __builtin_amdgcn_s_barrier();
        }
        cur ^= 1;
    }
#undef STAGE_
}

#define MFMA_CORE(AP, BP, LDA, LDB, KITERS)                              \
    __shared__ u16 As[2 * 128 * 32];                                     \
    __shared__ u16 Bs[2 * 128 * 32];                                     \
    const int t = threadIdx.x;                                           \
    const int wid = t >> 6, lane = t & 63;                               \
    const int quad = lane >> 4, l15 = lane & 15;                         \
    f32x4 acc[4][4];                                                     \
    _Pragma("unroll")                                                    \
    for (int i = 0; i < 4; ++i)                                          \
        _Pragma("unroll")                                                \
        for (int j = 0; j < 4; ++j) acc[i][j] = (f32x4){0.f,0.f,0.f,0.f};\
    mfma_mainloop(AP, BP, LDA, LDB, KITERS, acc, As, Bs);                \
    const int rbase = m0 + (wid >> 1) * 64;                              \
    const int cbase = n0 + (wid & 1) * 64;

// ---------------- R11 8-phase 256x256 core, BK=64 ----------------
// LDS: A = [2 buf][256 rows][64 cols] bf16 at elem 0 (32768 elems),
//      B same at elem 32768. Total 131072 B.
// Swizzle: LDS[r][c] holds G[r][c ^ ((r&7)<<3)] (involution, bank-fair).
// Staging unit "half" h of a tile = rows {h*64..h*64+63, 128+h*64..+63}
// (= exactly the rows the two wave-rows read in one phase for A).
// Per phase: stage ONE unit = 2 gl_lds16/thread (linear dest, per-lane
// pre-swizzled source col = ((lane&7)^(lane>>3))*8).
#define PH_MID()  do { __builtin_amdgcn_sched_barrier(0);                 \
    __builtin_amdgcn_s_barrier();                                         \
    asm volatile("s_waitcnt lgkmcnt(0)" ::: "memory");                    \
    __builtin_amdgcn_sched_barrier(0);                                    \
    __builtin_amdgcn_s_setprio(1); } while (0)
#define PH_END()  do { __builtin_amdgcn_s_setprio(0);                     \
    __builtin_amdgcn_sched_barrier(0);                                    \
    __builtin_amdgcn_s_barrier(); } while (0)
#define PH_END_VM(n) do { __builtin_amdgcn_s_setprio(0);                  \
    asm volatile("s_waitcnt vmcnt(" #n ")" ::: "memory");                 \
    __builtin_amdgcn_sched_barrier(0);                                    \
    __builtin_amdgcn_s_barrier(); } while (0)

#define DSA(d, half, Ar)                                                  \
    _Pragma("unroll")                                                     \
    for (int mi = 0; mi < 4; ++mi) {                                      \
        Ar[mi][0] = *(const bf16x8*)(aB0 + (d) * 16384 + ((half) * 4 + mi) * 1024); \
        Ar[mi][1] = *(const bf16x8*)(aB1 + (d) * 16384 + ((half) * 4 + mi) * 1024); \
    }
#define DSB(d, half, Br)                                                  \
    _Pragma("unroll")                                                     \
    for (int ni = 0; ni < 2; ++ni) {                                      \
        Br[ni][0] = *(const bf16x8*)(bB0 + (d) * 16384 + ((half) * 2 + ni) * 1024); \
        Br[ni][1] = *(const bf16x8*)(bB1 + (d) * 16384 + ((half) * 2 + ni) * 1024); \
    }
#define MMQ(mh, nh, Ar, Br)                                               \
    _Pragma("unroll")                                                     \
    for (int kk = 0; kk < 2; ++kk)                                        \
        _Pragma("unroll")                                                 \
        for (int mi = 0; mi < 4; ++mi)                                    \
            _Pragma("unroll")                                             \
            for (int ni = 0; ni < 2; ++ni)                                \
                acc[(mh) * 4 + mi][(nh) * 2 + ni] =                       \
                    __builtin_amdgcn_mfma_f32_16x16x32_bf16(              \
                        Ar[mi][kk], Br[ni][kk],                           \
                        acc[(mh) * 4 + mi][(nh) * 2 + ni], 0, 0, 0);
#define STG(isB, d, half, T)                                              \
    do {                                                                  \
        const u16* g_ = (isB) ? gB : gA;                                  \
        const int ld_ = (isB) ? ldb : lda;                                \
        u16* s_ = smem + ((isB) ? 32768 : 0) + (d) * 16384 + (half) * 4096 + sdst; \
        gl_lds16(g_ + (size_t)((half) * 64) * ld_ + (T) * 64, s_);        \
        gl_lds16(g_ + (size_t)((half) * 64 + 128) * ld_ + (T) * 64, s_ + 8192); \
    } while (0)

__device__ __forceinline__ void mfma8p_mainloop(
    const u16* __restrict__ A, const u16* __restrict__ B,
    int lda, int ldb, int ntiles,
    f32x4 (&acc)[8][4], u16* smem) {
    const int t = threadIdx.x;
    const int w = t >> 6, lane = t & 63;
    const int wr = w >> 2, wc = w & 3;
    const int quad = lane >> 4, l15 = lane & 15;

    // staging precompute (linear LDS dest, pre-swizzled global source)
    const int srow = w * 8 + (lane >> 3);                 // row within 64-chunk
    const int cofs = ((lane & 7) ^ (lane >> 3)) * 8;      // swizzled source col
    const int sdst = w * 512 + lane * 8;                  // elem off inside unit
    const u16* gA = A + (size_t)srow * lda + cofs;
    const u16* gB = B + (size_t)srow * ldb + cofs;

    // read precompute: col = (kk*32) ^ q, q = (quad*8) ^ ((l15&7)<<3)
    const int q = (quad * 8) ^ ((l15 & 7) << 3);
    const u16* aB0 = smem + (wr * 128 + l15) * 64 + q;
    const u16* aB1 = smem + (wr * 128 + l15) * 64 + (q ^ 32);
    const u16* bB0 = smem + 32768 + (wc * 64 + l15) * 64 + q;
    const u16* bB1 = smem + 32768 + (wc * 64 + l15) * 64 + (q ^ 32);

    // prologue: T0 all 4 units -> buf0; T1 units A0,B1,A1 -> buf1
    STG(0, 0, 0, 0); STG(0, 0, 1, 0); STG(1, 0, 0, 0); STG(1, 0, 1, 0);
    STG(0, 1, 0, 1); STG(1, 1, 1, 1); STG(0, 1, 1, 1);
    asm volatile("s_waitcnt vmcnt(6)" ::: "memory");
    __builtin_amdgcn_s_barrier();

    bf16x8 a[4][2], b[2][2], c[2][2];
    const int NI = ntiles >> 1;
    for (int i = 0; i < NI - 1; ++i) {
        const int T1t = 2 * i + 1, N0 = 2 * i + 2, N1 = 2 * i + 3;
        // p0
        DSA(0, 0, a) DSB(0, 0, b)
        STG(1, 1, 0, T1t);
        PH_MID(); MMQ(0, 0, a, b) PH_END();
        // p1
        DSB(0, 1, c)
        STG(0, 0, 0, N0);
        PH_MID(); MMQ(0, 1, a, c) PH_END();
        // p2
        DSA(0, 1, a)
        STG(1, 0, 1, N0);
        PH_MID(); MMQ(1, 1, a, c) PH_END();
        // p3
        STG(0, 0, 1, N0);
        PH_MID(); MMQ(1, 0, a, b) PH_END_VM(6);
        // p4
        DSA(1, 0, a) DSB(1, 0, b)
        STG(1, 0, 0, N0);
        PH_MID(); MMQ(0, 0, a, b) PH_END();
        // p5
        DSB(1, 1, c)
        STG(0, 1, 0, N1);
        PH_MID(); MMQ(0, 1, a, c) PH_END();
        // p6
        DSA(1, 1, a)
        STG(1, 1, 1, N1);
        PH_MID(); MMQ(1, 1, a, c) PH_END();
        // p7
        STG(0, 1, 1, N1);
        PH_MID(); MMQ(1, 0, a, b) PH_END_VM(6);
    }
    // last iter (no next-tile staging)
    {
        const int T1t = 2 * NI - 1;
        DSA(0, 0, a) DSB(0, 0, b)
        STG(1, 1, 0, T1t);
        PH_MID(); MMQ(0, 0, a, b) PH_END();
        DSB(0, 1, c)
        PH_MID(); MMQ(0, 1, a, c) PH_END();
        DSA(0, 1, a)
        PH_MID(); MMQ(1, 1, a, c) PH_END();
        PH_MID(); MMQ(1, 0, a, b) PH_END_VM(0);
        DSA(1, 0, a) DSB(1, 0, b)
        PH_MID(); MMQ(0, 0, a, b) PH_END();
        DSB(1, 1, c)
        PH_MID(); MMQ(0, 1, a, c) PH_END();
        DSA(1, 1, a)
        PH_MID(); MMQ(1, 1, a, c) PH_END();
        PH_MID(); MMQ(1, 0, a, b) PH_END();
    }
}

// k1: h1[(b*C+c)][t] = yat(xT, twb); M=49152 N=384 K=224 (R9 core).
__global__ __launch_bounds__(256) void k1_token_yat(
    const u16* __restrict__ xT, const u16* __restrict__ twb,
    const float* __restrict__ tb, const float* __restrict__ twn,
    const float* __restrict__ xn1, const float* __restrict__ alpha, float sb,
    u16* __restrict__ h1) {
    const int m0 = (blockIdx.x + blockIdx.y * 8) * 128;
    const int n0 = blockIdx.z * 128;
    MFMA_CORE(xT + (size_t)m0 * PPAD, twb + (size_t)n0 * PPAD, PPAD, PPAD, PPAD / 32)
    float scale = powf(sqrtf(sb), alpha[0]);
    #pragma unroll
    for (int i = 0; i < 4; ++i) {
        #pragma unroll
        for (int j = 0; j < 4; ++j) {
            int col = cbase + j * 16 + l15;
            float bn = tb[col], wnn = twn[col];
            #pragma unroll
            for (int reg = 0; reg < 4; ++reg) {
                int row = rbase + i * 16 + quad * 4 + reg;
                float dnb = acc[i][j][reg];
                float dot = dnb + bn;
                float dist = wnn + xn1[row] - 2.f * dnb;
                h1[(size_t)row * TM_ + col] = f2bf(scale * dot * dot / (dist + EPSY));
            }
        }
    }
}

// k3: h3 = yat(x1b, cwb); M=12544 N=3072 K=768. 8-phase 256² core.
// grid (8,7,12): mt = x + y*8 (XCD stripe, guard <49), n-tile = z.
__global__ __launch_bounds__(512, 2) void k3_chan_yat(
    const u16* __restrict__ x1b, const u16* __restrict__ cwb,
    const float* __restrict__ cb, const float* __restrict__ cwn,
    const float* __restrict__ xn2, const float* __restrict__ alpha, float sb,
    u16* __restrict__ h3) {
    __shared__ __align__(16) u16 smem[65536];
    const int mt = blockIdx.x + blockIdx.y * 8;
    if (mt >= (B_ * P_) / 256) return;
    const int m0 = mt * 256;
    const int n0 = blockIdx.z * 256;
    const int t = threadIdx.x;
    const int w = t >> 6, l = t & 63;
    const int wr = w >> 2, wc = w & 3;
    const int quad = l >> 4, l15 = l & 15;
    f32x4 acc[8][4];
    #pragma unroll
    for (int m = 0; m < 8; ++m)
        #pragma unroll
        for (int n = 0; n < 4; ++n) acc[m][n] = (f32x4){0.f, 0.f, 0.f, 0.f};
    mfma8p_mainloop(x1b + (size_t)m0 * C_, cwb + (size_t)n0 * C_,
                    C_, C_, C_ / 64, acc, smem);
    const int rbase = m0 + wr * 128;
    const int cbase = n0 + wc * 64;
    float scale = powf(sqrtf(sb), alpha[0]);
    #pragma unroll
    for (int m = 0; m < 8; ++m) {
        #pragma unroll
        for (int n = 0; n < 4; ++n) {
            int col = cbase + n * 16 + l15;
            float bn = cb[col], wnn = cwn[col];
            #pragma unroll
            for (int reg = 0; reg < 4; ++reg) {
                int row = rbase + m * 16 + quad * 4 + reg;
                float dnb = acc[m][n][reg];
                float dot = dnb + bn;
                float dist = wnn + xn2[row] - 2.f * dnb;
                h3[(size_t)row * CM_ + col] = f2bf(scale * dot * dot / (dist + EPSY));
            }
        }
    }
}

// k2: x1b = bf16(x + w2 . h1[b]^T + b2); fused xn2 row-norm atomics (R9 core).
__global__ __launch_bounds__(256) void k2_token_out(
    const u16* __restrict__ w2b, const u16* __restrict__ h1,
    const float* __restrict__ b2, const float* __restrict__ x,
    float* __restrict__ xn2, u16* __restrict__ x1b) {
    const int m0 = blockIdx.x * 128, n0 = blockIdx.y * 128;
    const u16* Bz = h1 + (size_t)blockIdx.z * C_ * TM_;
    MFMA_CORE(w2b + (size_t)m0 * TM_, Bz + (size_t)n0 * TM_, TM_, TM_, TM_ / 32)
    const float* rz = x + (size_t)blockIdx.z * P_ * C_;
    u16* oz = x1b + (size_t)blockIdx.z * P_ * C_;
    float* xrow = xn2 + (size_t)blockIdx.z * P_;
    #pragma unroll
    for (int i = 0; i < 4; ++i) {
        #pragma unroll
        for (int reg = 0; reg < 4; ++reg) {
            int row = rbase + i * 16 + quad * 4 + reg;
            if (row < P_) {
                float bm = b2[row];
                float s = 0.f;
                #pragma unroll
                for (int j = 0; j < 4; ++j) {
                    int col = cbase + j * 16 + l15;
                    float v = acc[i][j][reg] + bm + rz[(size_t)row * C_ + col];
                    u16 h = f2bf(v);
                    oz[(size_t)row * C_ + col] = h;
                    float vb = bf2f(h);
                    s = fmaf(vb, vb, s);
                }
                s += __shfl_xor(s, 1, 64);
                s += __shfl_xor(s, 2, 64);
                s += __shfl_xor(s, 4, 64);
                s += __shfl_xor(s, 8, 64);
                if (l15 == 0) atomicAdd(&xrow[row], s);
            }
        }
    }
}

// k4 split-K on 8-phase 256² core: grid (8,7,3*nsplit): n0=(z%3)*256, ks=z/3.
__global__ __launch_bounds__(512, 2) void k4_split(
    const u16* __restrict__ h3, const u16* __restrict__ w4b,
    u16* __restrict__ pbuf, int KK) {
    __shared__ __align__(16) u16 smem[65536];
    const int mt = blockIdx.x + blockIdx.y * 8;
    if (mt >= (B_ * P_) / 256) return;
    const int m0 = mt * 256;
    const int nz = blockIdx.z;
    const int n0 = (nz % 3) * 256;
    const int ks = nz / 3;
    const int kbase = ks * KK;
    const int t = threadIdx.x;
    const int w = t >> 6, l = t & 63;
    const int wr = w >> 2, wc = w & 3;
    const int quad = l >> 4, l15 = l & 15;
    f32x4 acc[8][4];
    #pragma unroll
    for (int m = 0; m < 8; ++m)
        #pragma unroll
        for (int n = 0; n < 4; ++n) acc[m][n] = (f32x4){0.f, 0.f, 0.f, 0.f};
    mfma8p_mainloop(h3 + (size_t)m0 * CM_ + kbase, w4b + (size_t)n0 * CM_ + kbase,
                    CM_, CM_, KK / 64, acc, smem);
    const int rbase = m0 + wr * 128;
    const int cbase = n0 + wc * 64;
    u16* dst = pbuf + (size_t)ks * ((size_t)B_ * P_ * C_);
    #pragma unroll
    for (int m = 0; m < 8; ++m) {
        #pragma unroll
        for (int n = 0; n < 4; ++n) {
            int col = cbase + n * 16 + l15;
            #pragma unroll
            for (int reg = 0; reg < 4; ++reg) {
                int row = rbase + m * 16 + quad * 4 + reg;
                dst[(size_t)row * C_ + col] = f2bf(acc[m][n][reg]);
            }
        }
    }
}

// reduce: out = sum(bf16 pbuf[0..NS-1]) + bf2f(x1b) + b4
template <int NS>
__global__ __launch_bounds__(256) void k4_reduce(
    float* __restrict__ outp, const u16* __restrict__ pbuf,
    const u16* __restrict__ x1b, const float* __restrict__ b4) {
    int idx = blockIdx.x * 256 + threadIdx.x;      // < B*P*C/4
    int c = (idx * 4) % C_;
    ushort4 r = ((const ushort4*)x1b)[idx];
    float4 o;
    o.x = bf2f(r.x) + b4[c + 0];
    o.y = bf2f(r.y) + b4[c + 1];
    o.z = bf2f(r.z) + b4[c + 2];
    o.w = bf2f(r.w) + b4[c + 3];
    const size_t stride4 = (size_t)B_ * P_ * C_ / 4;
    #pragma unroll
    for (int s = 0; s < NS; ++s) {
        ushort4 p = ((const ushort4*)pbuf)[idx + s * stride4];
        o.x += bf2f(p.x); o.y += bf2f(p.y); o.z += bf2f(p.z); o.w += bf2f(p.w);
    }
    ((float4*)outp)[idx] = o;
}

// fallback k4 (tiny ws): 128x64 tile BK=32
__global__ __launch_bounds__(256) void gemm_k4_fb(
    const u16* __restrict__ A, const u16* __restrict__ Bmat,
    const float* __restrict__ biasN, const u16* __restrict__ resB,
    float* __restrict__ Fout) {
    __shared__ u16 As[128 * 32];
    __shared__ u16 Bs[64 * 32];
    const int t = threadIdx.x;
    const int wid = t >> 6, lane = t & 63;
    const int quad = lane >> 4, l15 = lane & 15;
    const int m0 = blockIdx.x * 128, n0 = blockIdx.y * 64;
    f32x4 acc[4][2];
    #pragma unroll
    for (int i = 0; i < 4; ++i)
        #pragma unroll
        for (int j = 0; j < 2; ++j) acc[i][j] = (f32x4){0.f, 0.f, 0.f, 0.f};
    const u16* Aw = As + (wid >> 1) * (64 * 32);
    const u16* Bw = Bs + (wid & 1) * (32 * 32);
    const int arow = t >> 2, akc = (t & 3) * 8;
    for (int k0 = 0; k0 < CM_; k0 += 32) {
        gl_lds16(A + (size_t)(m0 + arow) * CM_ + k0 + akc,      As + wid * 512);
        gl_lds16(A + (size_t)(m0 + 64 + arow) * CM_ + k0 + akc, As + 2048 + wid * 512);
        gl_lds16(Bmat + (size_t)(n0 + arow) * CM_ + k0 + akc,   Bs + wid * 512);
        __syncthreads();
        bf16x8 af[4], bfr[2];
        #pragma unroll
        for (int i = 0; i < 4; ++i)
            af[i] = *(const bf16x8*)(Aw + ((i * 16 + l15) * 32 + quad * 8));
        #pragma unroll
        for (int j = 0; j < 2; ++j)
            bfr[j] = *(const bf16x8*)(Bw + ((j * 16 + l15) * 32 + quad * 8));
        #pragma unroll
        for (int i = 0; i < 4; ++i)
            #pragma unroll
            for (int j = 0; j < 2; ++j)
                acc[i][j] = __builtin_amdgcn_mfma_f32_16x16x32_bf16(af[i], bfr[j], acc[i][j], 0, 0, 0);
        __syncthreads();
    }
    const int rbase = m0 + (wid >> 1) * 64;
    const int cbase = n0 + (wid & 1) * 32;
    #pragma unroll
    for (int i = 0; i < 4; ++i) {
        #pragma unroll
        for (int j = 0; j < 2; ++j) {
            int col = cbase + j * 16 + l15;
            float bn = biasN[col];
            #pragma unroll
            for (int reg = 0; reg < 4; ++reg) {
                int row = rbase + i * 16 + quad * 4 + reg;
                float v = acc[i][j][reg] + bn + bf2f(resB[(size_t)row * C_ + col]);
                Fout[(size_t)row * C_ + col] = v;
            }
        }
    }
}

extern "C" void kernel_launch(void* const* d_in, const int* in_sizes, int n_in,
                              void* d_out, int out_size, void* d_ws, size_t ws_size,
                              hipStream_t stream) {
    const float* x  = (const float*)d_in[0];
    const float* tw = (const float*)d_in[1];
    const float* tb = (const float*)d_in[2];
    const float* ta = (const float*)d_in[3];
    const float* w2 = (const float*)d_in[4];
    const float* b2 = (const float*)d_in[5];
    const float* cw = (const float*)d_in[6];
    const float* cb = (const float*)d_in[7];
    const float* ca = (const float*)d_in[8];
    const float* w4 = (const float*)d_in[9];
    const float* b4 = (const float*)d_in[10];
    float* out = (float*)d_out;

    // ---- workspace layout (aliased) ----
    char* ws = (char*)d_ws;
    u16* h1 = (u16*)ws;                                    // B*C*TM (37.7 MB)
    u16* xT = (u16*)(ws + 37748736);                       // (B*C) x 224 (22 MB)
    u16* h3 = (u16*)ws;                                    // (B*P) x CM (77 MB)
    size_t off = 77070336;
    u16* x1b = (u16*)(ws + off); off += (size_t)B_ * P_ * C_ * 2;
    u16* twb = (u16*)(ws + off); off += (size_t)TM_ * PPAD * 2;
    u16* w2b = (u16*)(ws + off); off += (size_t)256 * TM_ * 2;
    u16* cwb = (u16*)(ws + off); off += (size_t)CM_ * C_ * 2;
    u16* w4b = (u16*)(ws + off); off += (size_t)C_ * CM_ * 2;
    float* xn1 = (float*)(ws + off); off += (size_t)B_ * C_ * 4;
    float* xn2 = (float*)(ws + off); off += (size_t)B_ * P_ * 4;
    float* twn = (float*)(ws + off); off += (size_t)TM_ * 4;
    float* cwn = (float*)(ws + off); off += (size_t)CM_ * 4;
    u16* pbuf = (u16*)(ws + off);                          // bf16 split-K partials
    const size_t psz = (size_t)B_ * P_ * C_ * 2;           // 19,267,584 per buffer

    int nsplit = 1;
    if (ws_size >= off + 4 * psz)      nsplit = 4;
    else if (ws_size >= off + 2 * psz) nsplit = 2;

    const float SBT = (float)TM_ / logf((float)TM_ + 1.0f);
    const float SBC = (float)CM_ / logf((float)CM_ + 1.0f);

    // ---- prep ----
    hipMemsetAsync(xn1, 0, (size_t)(B_ * C_ + B_ * P_) * 4, stream);
    k_prep_weights<<<3552, 256, 0, stream>>>(tw, twb, twn, cw, cwb, cwn,
                                             w2, w2b, w4, w4b);
    k_prep_xT<<<dim3(PPAD / 32, C_ / 32, B_), 256, 0, stream>>>(x, xT, xn1);

    // ---- k1: M=49152 N=384 K=224 ; XCD-swizzled grid (8,48,3) ----
    k1_token_yat<<<dim3(8, 48, 3), 256, 0, stream>>>(
        xT, twb, tb, twn, xn1, ta, SBT, h1);

    // ---- k2: M=256 N=768 K=384, per-batch ----
    k2_token_out<<<dim3(2, C_ / 128, B_), 256, 0, stream>>>(
        w2b, h1, b2, x, xn2, x1b);

    // ---- k3: M=12544 N=3072 K=768 ; 8-phase 256² tile, grid (8,7,12) ----
    k3_chan_yat<<<dim3(8, 7, 12), 512, 0, stream>>>(
        x1b, cwb, cb, cwn, xn2, ca, SBC, h3);

    // ---- k4: M=12544 N=768 K=3072, split-K bf16 partials, 8-phase 256² ----
    if (nsplit > 1) {
        k4_split<<<dim3(8, 7, 3 * nsplit), 512, 0, stream>>>(
            h3, w4b, pbuf, CM_ / nsplit);
        int n4 = B_ * P_ * C_ / 4;
        if (nsplit == 4)
            k4_reduce<4><<<(n4 + 255) / 256, 256, 0, stream>>>(out, pbuf, x1b, b4);
        else
            k4_reduce<2><<<(n4 + 255) / 256, 256, 0, stream>>>(out, pbuf, x1b, b4);
    } else {
        gemm_k4_fb<<<dim3(B_ * P_ / 128, C_ / 64), 256, 0, stream>>>(
            h3, w4b, b4, x1b, out);
    }
}